// Round 6
// baseline (157.824 us; speedup 1.0000x reference)
//
#include <hip/hip_runtime.h>

// HolonomyAttention: out = softmax_causal((Q @ C_h) K^T / sqrt(D)) V
// B=2 H=16 T=2048 D=64, fp32 in/out.
// Round 15: r14's LDS staging was NEUTRAL (attn ~34us in r10/r12/r14 alike)
// -> bottleneck is operand bytes per wave, not fetch mechanism. Fix:
// 2x arithmetic intensity: block = 128 q-rows, 4 waves x 32 rows (2 strips),
// one 16KB K+V stage serves 128 rows. LDS-read traffic 541->270MB, DMA
// 277->143MB. Wave-uniform compute-skip handles causal boundary; block
// pairing (p, 15-p) per CU balances the triangle exactly (34 tiles/CU).
// prep kernels unchanged from r14 (plane-split frag layout).

typedef __attribute__((ext_vector_type(8))) short short8;           // 8 bf16
typedef __attribute__((ext_vector_type(8))) unsigned short ushort8;
typedef __attribute__((ext_vector_type(4))) float f32x4;
typedef __attribute__((ext_vector_type(2))) _Float16 half2v;
typedef __attribute__((ext_vector_type(4))) _Float16 half4;
typedef __attribute__((ext_vector_type(8))) _Float16 half8;

constexpr int Tc = 2048;
constexpr int Dc = 64;
constexpr size_t REGION = (size_t)32 * Tc * Dc;   // 4,194,304 elems = 8 MiB u16

__device__ inline unsigned short f2bf(float f) {   // fp32 -> bf16 RNE
    union { float f; unsigned u; } x; x.f = f;
    return (unsigned short)((x.u + 0x7fffu + ((x.u >> 16) & 1u)) >> 16);
}

__device__ inline half2v pkrtz(float a, float b) {
    return __builtin_bit_cast(half2v, __builtin_amdgcn_cvt_pkrtz(a, b));
}

#define MFMA_BF16_K32(a, b, c) __builtin_amdgcn_mfma_f32_16x16x32_bf16((a), (b), (c), 0, 0, 0)
#define MFMA_F16_K16(a, b, c)  __builtin_amdgcn_mfma_f32_16x16x16f16((a), (b), (c), 0, 0, 0)

// async global->LDS copy: per-lane global addr, wave-uniform LDS base,
// HW deposits at base + lane*16.
typedef __attribute__((address_space(3))) unsigned int        lds_u32;
typedef const __attribute__((address_space(1))) unsigned int  glob_u32;
__device__ __attribute__((always_inline)) inline void gl_lds16(const void* g, void* l) {
    __builtin_amdgcn_global_load_lds((glob_u32*)g, (lds_u32*)l, 16, 0, 0);
}

// ---------------------------------------------------------------------------
// Kernel 0: C^T B-operand fragments per head (tiny, one-time).
// ---------------------------------------------------------------------------
__global__ __launch_bounds__(256, 1)
void holo_cfrag(const float* __restrict__ Cp, unsigned short* __restrict__ cfrag_g)
{
    const int t = threadIdx.x, lane = t & 63, eb = t >> 6;
    const int l15 = lane & 15, quad = lane >> 4;
    const int h = blockIdx.x;
    const float* Cg = Cp + (size_t)h * Dc * Dc;
    #pragma unroll
    for (int half = 0; half < 2; ++half) {
        short8 b;
        #pragma unroll
        for (int jj = 0; jj < 8; ++jj) {
            const int d = half * 32 + quad * 8 + jj;
            b[jj] = (short)f2bf(Cg[d * Dc + eb * 16 + l15]);
        }
        *(short8*)(&cfrag_g[(((size_t)h * 4 + eb) * 2 + half) * 512 + lane * 8]) = b;
    }
}

// ---------------------------------------------------------------------------
// Kernel 1: prepass, one block per (bh, 64-row tile st). LDS-staged.
// K/V fragment tiles PLANE-SPLIT within each 8KB tile:
//   ktile[0..2047]    = kf0 chunks, (tn*64+lane)*8 u16   (16B per lane)
//   ktile[2048..4095] = kf1 chunks
//   vtile likewise (v0 plane | v1 plane, f16)
// ---------------------------------------------------------------------------
__global__ __launch_bounds__(256, 4)
void holo_prep8(const float* __restrict__ Qp, const float* __restrict__ Kp,
                const float* __restrict__ Vp,
                const unsigned short* __restrict__ cfrag_g,
                unsigned short* __restrict__ qfrag_g,
                unsigned short* __restrict__ kfrag_g,
                _Float16* __restrict__ vfrag_g)
{
    __shared__ unsigned short kt[64 * 72];   // K tile bf16 natural [s][d]
    __shared__ unsigned short qt[64 * 72];   // Q tile bf16 natural [r][d]
    __shared__ _Float16      vt[64 * 72];    // V tile f16 natural [s][d]
    __shared__ unsigned short pf[64 * 72];   // Qrot C->B-frag round trip

    const int t = threadIdx.x, lane = t & 63, w = t >> 6;
    const int l15 = lane & 15, quad = lane >> 4, wb = w * 16;
    const int n = blockIdx.x, bh = n >> 5, st = n & 31, h = bh & 15;
    const int s0 = st * 64;

    const float* Qg = Qp + ((size_t)bh * Tc + s0) * Dc;
    const float* Kg = Kp + ((size_t)bh * Tc + s0) * Dc;
    const float* Vg = Vp + ((size_t)bh * Tc + s0) * Dc;

    // ---- stage all three tiles (coalesced float4 reads, cvt, LDS write) ----
    #pragma unroll
    for (int kk = 0; kk < 4; ++kk) {
        const int flat = kk * 1024 + t * 4;
        const int r = flat >> 6, d0 = flat & 63;
        float4 kv = *(const float4*)(&Kg[flat]);
        ushort4 kp; kp.x = f2bf(kv.x); kp.y = f2bf(kv.y); kp.z = f2bf(kv.z); kp.w = f2bf(kv.w);
        *(ushort4*)(&kt[r * 72 + d0]) = kp;
        float4 qv = *(const float4*)(&Qg[flat]);
        ushort4 qp; qp.x = f2bf(qv.x); qp.y = f2bf(qv.y); qp.z = f2bf(qv.z); qp.w = f2bf(qv.w);
        *(ushort4*)(&qt[r * 72 + d0]) = qp;
        float4 vv = *(const float4*)(&Vg[flat]);
        half4 vp;
        vp[0] = (_Float16)vv.x; vp[1] = (_Float16)vv.y;
        vp[2] = (_Float16)vv.z; vp[3] = (_Float16)vv.w;
        *(half4*)(&vt[r * 72 + d0]) = vp;
    }
    __syncthreads();

    // ---- K fragments (wave w handles tn = w): plane-split writes ----
    {
        const int row = wb + l15;
        ushort8 p0 = *(const ushort8*)(&kt[row * 72 + quad * 8]);
        ushort8 p1 = *(const ushort8*)(&kt[row * 72 + 32 + quad * 8]);
        unsigned short* ktile = kfrag_g + (size_t)(bh * 32 + st) * 4096;
        *(ushort8*)(&ktile[(w * 64 + lane) * 8])        = p0;
        *(ushort8*)(&ktile[2048 + (w * 64 + lane) * 8]) = p1;
    }

    // ---- V fragments: plane-split writes ----
    {
        half8 v0, v1;
        #pragma unroll
        for (int dn = 0; dn < 2; ++dn)
            #pragma unroll
            for (int i = 0; i < 4; ++i)
                v0[dn * 4 + i] = vt[(wb + quad * 4 + i) * 72 + dn * 16 + l15];
        #pragma unroll
        for (int dn = 0; dn < 2; ++dn)
            #pragma unroll
            for (int i = 0; i < 4; ++i)
                v1[dn * 4 + i] = vt[(wb + quad * 4 + i) * 72 + (dn + 2) * 16 + l15];
        _Float16* vtile = vfrag_g + (size_t)(bh * 32 + st) * 4096;
        *(half8*)(&vtile[(w * 64 + lane) * 8])        = v0;
        *(half8*)(&vtile[2048 + (w * 64 + lane) * 8]) = v1;
    }

    // ---- Qrot strip (rows s0+wb..+15): A from qt LDS, B from cfrag ----
    {
        short8 a0 = *(const short8*)(&qt[(wb + l15) * 72 + quad * 8]);
        short8 a1 = *(const short8*)(&qt[(wb + l15) * 72 + 32 + quad * 8]);
        #pragma unroll
        for (int eb = 0; eb < 4; ++eb) {
            short8 b0 = *(const short8*)(&cfrag_g[(((size_t)h * 4 + eb) * 2 + 0) * 512 + lane * 8]);
            short8 b1 = *(const short8*)(&cfrag_g[(((size_t)h * 4 + eb) * 2 + 1) * 512 + lane * 8]);
            f32x4 c = {0.f, 0.f, 0.f, 0.f};
            c = MFMA_BF16_K32(a0, b0, c);
            c = MFMA_BF16_K32(a1, b1, c);
            #pragma unroll
            for (int i = 0; i < 4; ++i)   // fold 0.125 * log2(e)
                pf[(wb + quad * 4 + i) * 72 + eb * 16 + l15] = f2bf(c[i] * 0.18033688f);
        }
        __threadfence_block();   // wave-local rows: order writes before reads
        short8 fa0 = *(const short8*)(&pf[(wb + l15) * 72 + quad * 8]);
        short8 fa1 = *(const short8*)(&pf[(wb + l15) * 72 + 32 + quad * 8]);
        const size_t strip = (size_t)bh * 128 + st * 4 + w;
        *(short8*)(&qfrag_g[strip * 1024 + lane * 8]) = fa0;
        *(short8*)(&qfrag_g[strip * 1024 + 512 + lane * 8]) = fa1;
    }
}

// ---------------------------------------------------------------------------
// Kernel 2: attention. 1 block = 128 q-rows (2 qi-tiles), 4 waves x 32 rows
// (2 strips each). LDS double-buffered K+V staging via global_load_lds;
// one 16KB stage serves all 128 rows. JIT ds_read_b128 operands, K/V regs
// reused across both strips. Wave-uniform compute-skip at causal boundary.
// Block pairing: CU gets (p, 15-p) -> 34 block-tiles per CU, no tail.
// ---------------------------------------------------------------------------
__global__ __launch_bounds__(256, 2)
void holo_attn15(const unsigned short* __restrict__ qfrag_g,
                 const unsigned short* __restrict__ kfrag_g,
                 const _Float16* __restrict__ vfrag_g,
                 float* __restrict__ Op)
{
    __shared__ unsigned short bufK[2][4096];   // 2 x 8KB, plane-split layout
    __shared__ _Float16      bufV[2][4096];    // 2 x 8KB

    const int t = threadIdx.x, lane = t & 63, wid = t >> 6;
    const int l15 = lane & 15, quad = lane >> 4;

    // grid 512 = 8 xcd x 64 seq. seq = (u, v, w5): bh_local = v*2+w5,
    // p = w5 ? u : 15-u. Round-robin dispatch pairs seq c with c+32 on one
    // CU -> that CU gets p = 15-u and p = u: constant 34 tiles/CU.
    const int id = blockIdx.x;
    const int xcd = id & 7, seq = id >> 3;
    const int u = seq & 15, v = (seq >> 4) & 1, w5 = (seq >> 5) & 1;
    const int bh = xcd * 4 + v * 2 + w5;
    const int p  = w5 ? u : 15 - u;          // 128-row block index (0..15)
    const int jmax  = 2 * p + 1;             // last k-tile for this block
    const int jdiag = 2 * p + (wid >> 1);    // this wave's diagonal tile

    const char* kbase = (const char*)(kfrag_g + (size_t)bh * 32 * 4096);
    const char* vbase = (const char*)(vfrag_g + (size_t)bh * 32 * 4096);

    // ---- stage tile 0 into ring slot 0 (async, issued first) ----
    gl_lds16(kbase + wid * 1024 + lane * 16,        &bufK[0][wid * 512]);
    gl_lds16(kbase + 4096 + wid * 1024 + lane * 16, &bufK[0][2048 + wid * 512]);
    gl_lds16(vbase + wid * 1024 + lane * 16,        &bufV[0][wid * 512]);
    gl_lds16(vbase + 4096 + wid * 1024 + lane * 16, &bufV[0][2048 + wid * 512]);

    // Qrot B-fragments for this wave's two strips (scale*log2e folded in)
    short8 qa0[2], qa1[2];
    #pragma unroll
    for (int s2 = 0; s2 < 2; ++s2) {
        const size_t strip = (size_t)bh * 128 + p * 8 + wid * 2 + s2;
        qa0[s2] = *(const short8*)(&qfrag_g[strip * 1024 + lane * 8]);
        qa1[s2] = *(const short8*)(&qfrag_g[strip * 1024 + 512 + lane * 8]);
    }

    f32x4 o[2][4];              // o[s2][dn][i]: O[q=l15][d=dn*16+quad*4+i]
    #pragma unroll
    for (int s2 = 0; s2 < 2; ++s2)
        #pragma unroll
        for (int dn = 0; dn < 4; ++dn) o[s2][dn] = f32x4{0.f, 0.f, 0.f, 0.f};
    float l2[2] = {0.f, 0.f};

    const int rowgA = p * 128 + wid * 32 + l15;   // strip 0 global q row
    const int rowgB = rowgA + 16;                 // strip 1

    asm volatile("s_waitcnt vmcnt(0)" ::: "memory");
    __builtin_amdgcn_sched_barrier(0);
    __syncthreads();

    int cur = 0;
    for (int j = 0; j <= jmax; ++j) {
        // ---- issue next tile's DMA into the other ring slot ----
        if (j < jmax) {
            const char* ks = kbase + (size_t)(j + 1) * 8192;
            const char* vs = vbase + (size_t)(j + 1) * 8192;
            const int nb = cur ^ 1;
            gl_lds16(ks + wid * 1024 + lane * 16,        &bufK[nb][wid * 512]);
            gl_lds16(ks + 4096 + wid * 1024 + lane * 16, &bufK[nb][2048 + wid * 512]);
            gl_lds16(vs + wid * 1024 + lane * 16,        &bufV[nb][wid * 512]);
            gl_lds16(vs + 4096 + wid * 1024 + lane * 16, &bufV[nb][2048 + wid * 512]);
        }

        // waves 0,1 have no valid rows on the block's last tile: skip
        // compute (wave-uniform) but still hit the barrier below.
        if (j <= jdiag) {
            const unsigned short* Kl = &bufK[cur][0];
            const _Float16*       Vl = &bufV[cur][0];

            // ---- S^T = K * Qrot^T, both strips share K regs ----
            f32x4 stA[4], stB[4];
            __builtin_amdgcn_s_setprio(1);
            #pragma unroll
            for (int tn = 0; tn < 4; ++tn) {
                short8 k0 = *(const short8*)(&Kl[(tn * 64 + lane) * 8]);
                short8 k1 = *(const short8*)(&Kl[2048 + (tn * 64 + lane) * 8]);
                f32x4 cA = {0.f, 0.f, 0.f, 0.f};
                cA = MFMA_BF16_K32(k0, qa0[0], cA);
                cA = MFMA_BF16_K32(k1, qa1[0], cA);
                stA[tn] = cA;
                f32x4 cB = {0.f, 0.f, 0.f, 0.f};
                cB = MFMA_BF16_K32(k0, qa0[1], cB);
                cB = MFMA_BF16_K32(k1, qa1[1], cB);
                stB[tn] = cB;
            }
            __builtin_amdgcn_s_setprio(0);

            // ---- mask + fixed-shift softmax; packed f16 cvt ----
            half4 paA[4], paB[4];
            #pragma unroll
            for (int tn = 0; tn < 4; ++tn) {
                float pA[4];
                #pragma unroll
                for (int i = 0; i < 4; ++i) {
                    float sv = stA[tn][i];
                    if (j == jdiag) {
                        const int colg = j * 64 + tn * 16 + quad * 4 + i;
                        if (colg > rowgA) sv = -1e30f;
                    }
                    pA[i] = __builtin_amdgcn_exp2f(sv);
                    l2[0] += pA[i];
                }
                half2v lo = pkrtz(pA[0], pA[1]), hi = pkrtz(pA[2], pA[3]);
                paA[tn] = __builtin_shufflevector(lo, hi, 0, 1, 2, 3);
            }
            #pragma unroll
            for (int tn = 0; tn < 4; ++tn) {
                float pB[4];
                #pragma unroll
                for (int i = 0; i < 4; ++i) {
                    float sv = stB[tn][i];
                    if (j == jdiag) {
                        const int colg = j * 64 + tn * 16 + quad * 4 + i;
                        if (colg > rowgB) sv = -1e30f;
                    }
                    pB[i] = __builtin_amdgcn_exp2f(sv);
                    l2[1] += pB[i];
                }
                half2v lo = pkrtz(pB[0], pB[1]), hi = pkrtz(pB[2], pB[3]);
                paB[tn] = __builtin_shufflevector(lo, hi, 0, 1, 2, 3);
            }

            // ---- O^T += V^T * P, both strips share V regs ----
            __builtin_amdgcn_s_setprio(1);
            #pragma unroll
            for (int tn = 0; tn < 4; ++tn) {
                half8 vl = *(const half8*)(&Vl[(tn * 64 + lane) * 8]);
                half8 vh = *(const half8*)(&Vl[2048 + (tn * 64 + lane) * 8]);
                half4 vf0 = __builtin_shufflevector(vl, vl, 0, 1, 2, 3);
                half4 vf1 = __builtin_shufflevector(vl, vl, 4, 5, 6, 7);
                half4 vf2 = __builtin_shufflevector(vh, vh, 0, 1, 2, 3);
                half4 vf3 = __builtin_shufflevector(vh, vh, 4, 5, 6, 7);
                o[0][0] = MFMA_F16_K16(vf0, paA[tn], o[0][0]);
                o[0][1] = MFMA_F16_K16(vf1, paA[tn], o[0][1]);
                o[0][2] = MFMA_F16_K16(vf2, paA[tn], o[0][2]);
                o[0][3] = MFMA_F16_K16(vf3, paA[tn], o[0][3]);
                o[1][0] = MFMA_F16_K16(vf0, paB[tn], o[1][0]);
                o[1][1] = MFMA_F16_K16(vf1, paB[tn], o[1][1]);
                o[1][2] = MFMA_F16_K16(vf2, paB[tn], o[1][2]);
                o[1][3] = MFMA_F16_K16(vf3, paB[tn], o[1][3]);
            }
            __builtin_amdgcn_s_setprio(0);
        }

        // ---- flip: next DMA landed + all waves done reading cur ----
        asm volatile("s_waitcnt vmcnt(0)" ::: "memory");
        __builtin_amdgcn_sched_barrier(0);
        __syncthreads();
        cur ^= 1;
    }

    // ---- per-strip row sums + epilogue (direct stores) ----
    #pragma unroll
    for (int s2 = 0; s2 < 2; ++s2) {
        float l = l2[s2];
        l += __shfl_xor(l, 16);
        l += __shfl_xor(l, 32);
        const float inv = 1.0f / l;
        const int rowg = rowgA + s2 * 16;
        float* dst = Op + ((size_t)bh * Tc + rowg) * Dc;
        #pragma unroll
        for (int dn = 0; dn < 4; ++dn) {
            float4 r;
            r.x = o[s2][dn][0] * inv; r.y = o[s2][dn][1] * inv;
            r.z = o[s2][dn][2] * inv; r.w = o[s2][dn][3] * inv;
            *(float4*)(&dst[dn * 16 + quad * 4]) = r;
        }
    }
}

extern "C" void kernel_launch(void* const* d_in, const int* in_sizes, int n_in,
                              void* d_out, int out_size, void* d_ws, size_t ws_size,
                              hipStream_t stream) {
    const float* Q = (const float*)d_in[0];
    const float* K = (const float*)d_in[1];
    const float* V = (const float*)d_in[2];
    // d_in[3] = causal mask (analytic — unused)
    const float* C = (const float*)d_in[4];
    float* O = (float*)d_out;

    unsigned short* qfrag_w = (unsigned short*)d_ws;              // 8 MiB
    unsigned short* kfrag_w = qfrag_w + REGION;                   // 8 MiB
    _Float16*       vfrag_w = (_Float16*)(kfrag_w + REGION);      // 8 MiB
    unsigned short* cfrag_w = (unsigned short*)(vfrag_w + REGION);// 128 KiB

    holo_cfrag<<<dim3(16), dim3(256), 0, stream>>>(C, cfrag_w);
    holo_prep8<<<dim3(1024), dim3(256), 0, stream>>>(Q, K, V, cfrag_w, qfrag_w, kfrag_w, vfrag_w);
    holo_attn15<<<dim3(512), dim3(256), 0, stream>>>(qfrag_w, kfrag_w, vfrag_w, O);
}

// Round 7
// 148.476 us; speedup vs baseline: 1.0630x; 1.0630x over previous
//
#include <hip/hip_runtime.h>

// HolonomyAttention: out = softmax_causal((Q @ C_h) K^T / sqrt(D)) V
// B=2 H=16 T=2048 D=64, fp32 in/out.
// Round 16: r15's 32-rows/wave intensity was right (VGPR 68, no spill,
// DMA halved) but 128-row blocks at grid 512 had a 16x work spread and
// 11% occupancy -> 53us. This round keeps the intensity and restores the
// proven balance: block = one 64-row (bh,qi) tile, 2 waves x 32 rows
// (128 threads), grid 1024 with the r9/r12 balanced per-CU qi mapping
// (66 tiles/CU exactly). LDS double-buffer staging unchanged.
// prep kernels unchanged (plane-split frag layout).

typedef __attribute__((ext_vector_type(8))) short short8;           // 8 bf16
typedef __attribute__((ext_vector_type(8))) unsigned short ushort8;
typedef __attribute__((ext_vector_type(4))) float f32x4;
typedef __attribute__((ext_vector_type(2))) _Float16 half2v;
typedef __attribute__((ext_vector_type(4))) _Float16 half4;
typedef __attribute__((ext_vector_type(8))) _Float16 half8;

constexpr int Tc = 2048;
constexpr int Dc = 64;
constexpr size_t REGION = (size_t)32 * Tc * Dc;   // 4,194,304 elems = 8 MiB u16

__device__ inline unsigned short f2bf(float f) {   // fp32 -> bf16 RNE
    union { float f; unsigned u; } x; x.f = f;
    return (unsigned short)((x.u + 0x7fffu + ((x.u >> 16) & 1u)) >> 16);
}

__device__ inline half2v pkrtz(float a, float b) {
    return __builtin_bit_cast(half2v, __builtin_amdgcn_cvt_pkrtz(a, b));
}

#define MFMA_BF16_K32(a, b, c) __builtin_amdgcn_mfma_f32_16x16x32_bf16((a), (b), (c), 0, 0, 0)
#define MFMA_F16_K16(a, b, c)  __builtin_amdgcn_mfma_f32_16x16x16f16((a), (b), (c), 0, 0, 0)

// async global->LDS copy: per-lane global addr, wave-uniform LDS base,
// HW deposits at base + lane*16.
typedef __attribute__((address_space(3))) unsigned int        lds_u32;
typedef const __attribute__((address_space(1))) unsigned int  glob_u32;
__device__ __attribute__((always_inline)) inline void gl_lds16(const void* g, void* l) {
    __builtin_amdgcn_global_load_lds((glob_u32*)g, (lds_u32*)l, 16, 0, 0);
}

// ---------------------------------------------------------------------------
// Kernel 0: C^T B-operand fragments per head (tiny, one-time).
// ---------------------------------------------------------------------------
__global__ __launch_bounds__(256, 1)
void holo_cfrag(const float* __restrict__ Cp, unsigned short* __restrict__ cfrag_g)
{
    const int t = threadIdx.x, lane = t & 63, eb = t >> 6;
    const int l15 = lane & 15, quad = lane >> 4;
    const int h = blockIdx.x;
    const float* Cg = Cp + (size_t)h * Dc * Dc;
    #pragma unroll
    for (int half = 0; half < 2; ++half) {
        short8 b;
        #pragma unroll
        for (int jj = 0; jj < 8; ++jj) {
            const int d = half * 32 + quad * 8 + jj;
            b[jj] = (short)f2bf(Cg[d * Dc + eb * 16 + l15]);
        }
        *(short8*)(&cfrag_g[(((size_t)h * 4 + eb) * 2 + half) * 512 + lane * 8]) = b;
    }
}

// ---------------------------------------------------------------------------
// Kernel 1: prepass, one block per (bh, 64-row tile st). LDS-staged.
// K/V fragment tiles PLANE-SPLIT within each 8KB tile:
//   ktile[0..2047]    = kf0 chunks, (tn*64+lane)*8 u16   (16B per lane)
//   ktile[2048..4095] = kf1 chunks
//   vtile likewise (v0 plane | v1 plane, f16)
// ---------------------------------------------------------------------------
__global__ __launch_bounds__(256, 4)
void holo_prep8(const float* __restrict__ Qp, const float* __restrict__ Kp,
                const float* __restrict__ Vp,
                const unsigned short* __restrict__ cfrag_g,
                unsigned short* __restrict__ qfrag_g,
                unsigned short* __restrict__ kfrag_g,
                _Float16* __restrict__ vfrag_g)
{
    __shared__ unsigned short kt[64 * 72];   // K tile bf16 natural [s][d]
    __shared__ unsigned short qt[64 * 72];   // Q tile bf16 natural [r][d]
    __shared__ _Float16      vt[64 * 72];    // V tile f16 natural [s][d]
    __shared__ unsigned short pf[64 * 72];   // Qrot C->B-frag round trip

    const int t = threadIdx.x, lane = t & 63, w = t >> 6;
    const int l15 = lane & 15, quad = lane >> 4, wb = w * 16;
    const int n = blockIdx.x, bh = n >> 5, st = n & 31, h = bh & 15;
    const int s0 = st * 64;

    const float* Qg = Qp + ((size_t)bh * Tc + s0) * Dc;
    const float* Kg = Kp + ((size_t)bh * Tc + s0) * Dc;
    const float* Vg = Vp + ((size_t)bh * Tc + s0) * Dc;

    // ---- stage all three tiles (coalesced float4 reads, cvt, LDS write) ----
    #pragma unroll
    for (int kk = 0; kk < 4; ++kk) {
        const int flat = kk * 1024 + t * 4;
        const int r = flat >> 6, d0 = flat & 63;
        float4 kv = *(const float4*)(&Kg[flat]);
        ushort4 kp; kp.x = f2bf(kv.x); kp.y = f2bf(kv.y); kp.z = f2bf(kv.z); kp.w = f2bf(kv.w);
        *(ushort4*)(&kt[r * 72 + d0]) = kp;
        float4 qv = *(const float4*)(&Qg[flat]);
        ushort4 qp; qp.x = f2bf(qv.x); qp.y = f2bf(qv.y); qp.z = f2bf(qv.z); qp.w = f2bf(qv.w);
        *(ushort4*)(&qt[r * 72 + d0]) = qp;
        float4 vv = *(const float4*)(&Vg[flat]);
        half4 vp;
        vp[0] = (_Float16)vv.x; vp[1] = (_Float16)vv.y;
        vp[2] = (_Float16)vv.z; vp[3] = (_Float16)vv.w;
        *(half4*)(&vt[r * 72 + d0]) = vp;
    }
    __syncthreads();

    // ---- K fragments (wave w handles tn = w): plane-split writes ----
    {
        const int row = wb + l15;
        ushort8 p0 = *(const ushort8*)(&kt[row * 72 + quad * 8]);
        ushort8 p1 = *(const ushort8*)(&kt[row * 72 + 32 + quad * 8]);
        unsigned short* ktile = kfrag_g + (size_t)(bh * 32 + st) * 4096;
        *(ushort8*)(&ktile[(w * 64 + lane) * 8])        = p0;
        *(ushort8*)(&ktile[2048 + (w * 64 + lane) * 8]) = p1;
    }

    // ---- V fragments: plane-split writes ----
    {
        half8 v0, v1;
        #pragma unroll
        for (int dn = 0; dn < 2; ++dn)
            #pragma unroll
            for (int i = 0; i < 4; ++i)
                v0[dn * 4 + i] = vt[(wb + quad * 4 + i) * 72 + dn * 16 + l15];
        #pragma unroll
        for (int dn = 0; dn < 2; ++dn)
            #pragma unroll
            for (int i = 0; i < 4; ++i)
                v1[dn * 4 + i] = vt[(wb + quad * 4 + i) * 72 + (dn + 2) * 16 + l15];
        _Float16* vtile = vfrag_g + (size_t)(bh * 32 + st) * 4096;
        *(half8*)(&vtile[(w * 64 + lane) * 8])        = v0;
        *(half8*)(&vtile[2048 + (w * 64 + lane) * 8]) = v1;
    }

    // ---- Qrot strip (rows s0+wb..+15): A from qt LDS, B from cfrag ----
    {
        short8 a0 = *(const short8*)(&qt[(wb + l15) * 72 + quad * 8]);
        short8 a1 = *(const short8*)(&qt[(wb + l15) * 72 + 32 + quad * 8]);
        #pragma unroll
        for (int eb = 0; eb < 4; ++eb) {
            short8 b0 = *(const short8*)(&cfrag_g[(((size_t)h * 4 + eb) * 2 + 0) * 512 + lane * 8]);
            short8 b1 = *(const short8*)(&cfrag_g[(((size_t)h * 4 + eb) * 2 + 1) * 512 + lane * 8]);
            f32x4 c = {0.f, 0.f, 0.f, 0.f};
            c = MFMA_BF16_K32(a0, b0, c);
            c = MFMA_BF16_K32(a1, b1, c);
            #pragma unroll
            for (int i = 0; i < 4; ++i)   // fold 0.125 * log2(e)
                pf[(wb + quad * 4 + i) * 72 + eb * 16 + l15] = f2bf(c[i] * 0.18033688f);
        }
        __threadfence_block();   // wave-local rows: order writes before reads
        short8 fa0 = *(const short8*)(&pf[(wb + l15) * 72 + quad * 8]);
        short8 fa1 = *(const short8*)(&pf[(wb + l15) * 72 + 32 + quad * 8]);
        const size_t strip = (size_t)bh * 128 + st * 4 + w;
        *(short8*)(&qfrag_g[strip * 1024 + lane * 8]) = fa0;
        *(short8*)(&qfrag_g[strip * 1024 + 512 + lane * 8]) = fa1;
    }
}

// ---------------------------------------------------------------------------
// Kernel 2: attention. 1 block = 1 (bh,qi) 64-row tile, 2 waves x 32 rows
// (2 strips each, K/V regs shared across strips). Grid 1024, balanced
// per-CU qi mapping (r9/r12: qi sums to 66 tiles on every CU). LDS
// double-buffered K+V staging via global_load_lds; JIT ds_read_b128.
// ---------------------------------------------------------------------------
__global__ __launch_bounds__(128, 2)
void holo_attn16(const unsigned short* __restrict__ qfrag_g,
                 const unsigned short* __restrict__ kfrag_g,
                 const _Float16* __restrict__ vfrag_g,
                 float* __restrict__ Op)
{
    __shared__ unsigned short bufK[2][4096];   // 2 x 8KB, plane-split layout
    __shared__ _Float16      bufV[2][4096];    // 2 x 8KB

    const int t = threadIdx.x, lane = t & 63, wid = t >> 6;   // wid in {0,1}
    const int l15 = lane & 15, quad = lane >> 4;

    // Balanced mapping (r9/r12): per CU qi set {m, 31-m, (m+16)&31, 31-((m+16)&31)}
    const int id = blockIdx.x;
    const int xcd = id & 7, m = (id >> 3) & 31, k = id >> 8;
    const int bh = xcd * 4 + k;
    const int mm = (k >= 2) ? ((m + 16) & 31) : m;
    const int qi = (k & 1) ? (31 - mm) : mm;
    const int q0 = qi * 64;

    const char* kbase = (const char*)(kfrag_g + (size_t)bh * 32 * 4096);
    const char* vbase = (const char*)(vfrag_g + (size_t)bh * 32 * 4096);

    // ---- stage tile 0 into ring slot 0 (8 loads per wave) ----
    #pragma unroll
    for (int s = 0; s < 2; ++s) {
        const int seg = wid * 2 + s;   // 0..3: 1KB segment within a plane
        gl_lds16(kbase + seg * 1024 + lane * 16,        &bufK[0][seg * 512]);
        gl_lds16(kbase + 4096 + seg * 1024 + lane * 16, &bufK[0][2048 + seg * 512]);
        gl_lds16(vbase + seg * 1024 + lane * 16,        &bufV[0][seg * 512]);
        gl_lds16(vbase + 4096 + seg * 1024 + lane * 16, &bufV[0][2048 + seg * 512]);
    }

    // Qrot B-fragments for this wave's two strips (scale*log2e folded in)
    short8 qa0[2], qa1[2];
    #pragma unroll
    for (int s2 = 0; s2 < 2; ++s2) {
        const size_t strip = (size_t)bh * 128 + qi * 4 + wid * 2 + s2;
        qa0[s2] = *(const short8*)(&qfrag_g[strip * 1024 + lane * 8]);
        qa1[s2] = *(const short8*)(&qfrag_g[strip * 1024 + 512 + lane * 8]);
    }

    f32x4 o[2][4];              // o[s2][dn][i]: O[q=l15][d=dn*16+quad*4+i]
    #pragma unroll
    for (int s2 = 0; s2 < 2; ++s2)
        #pragma unroll
        for (int dn = 0; dn < 4; ++dn) o[s2][dn] = f32x4{0.f, 0.f, 0.f, 0.f};
    float l2[2] = {0.f, 0.f};

    const int rowgA = q0 + wid * 32 + l15;   // strip 0 global q row
    const int rowgB = rowgA + 16;            // strip 1

    asm volatile("s_waitcnt vmcnt(0)" ::: "memory");
    __builtin_amdgcn_sched_barrier(0);
    __syncthreads();

    int cur = 0;
    for (int j = 0; j <= qi; ++j) {
        // ---- issue next tile's DMA into the other ring slot ----
        if (j < qi) {
            const char* ks = kbase + (size_t)(j + 1) * 8192;
            const char* vs = vbase + (size_t)(j + 1) * 8192;
            const int nb = cur ^ 1;
            #pragma unroll
            for (int s = 0; s < 2; ++s) {
                const int seg = wid * 2 + s;
                gl_lds16(ks + seg * 1024 + lane * 16,        &bufK[nb][seg * 512]);
                gl_lds16(ks + 4096 + seg * 1024 + lane * 16, &bufK[nb][2048 + seg * 512]);
                gl_lds16(vs + seg * 1024 + lane * 16,        &bufV[nb][seg * 512]);
                gl_lds16(vs + 4096 + seg * 1024 + lane * 16, &bufV[nb][2048 + seg * 512]);
            }
        }

        const unsigned short* Kl = &bufK[cur][0];
        const _Float16*       Vl = &bufV[cur][0];

        // ---- S^T = K * Qrot^T, both strips share K regs ----
        f32x4 stA[4], stB[4];
        __builtin_amdgcn_s_setprio(1);
        #pragma unroll
        for (int tn = 0; tn < 4; ++tn) {
            short8 k0 = *(const short8*)(&Kl[(tn * 64 + lane) * 8]);
            short8 k1 = *(const short8*)(&Kl[2048 + (tn * 64 + lane) * 8]);
            f32x4 cA = {0.f, 0.f, 0.f, 0.f};
            cA = MFMA_BF16_K32(k0, qa0[0], cA);
            cA = MFMA_BF16_K32(k1, qa1[0], cA);
            stA[tn] = cA;
            f32x4 cB = {0.f, 0.f, 0.f, 0.f};
            cB = MFMA_BF16_K32(k0, qa0[1], cB);
            cB = MFMA_BF16_K32(k1, qa1[1], cB);
            stB[tn] = cB;
        }
        __builtin_amdgcn_s_setprio(0);

        // ---- mask + fixed-shift softmax; packed f16 cvt ----
        half4 paA[4], paB[4];
        #pragma unroll
        for (int tn = 0; tn < 4; ++tn) {
            float pA[4];
            #pragma unroll
            for (int i = 0; i < 4; ++i) {
                float sv = stA[tn][i];
                if (j == qi) {
                    const int colg = j * 64 + tn * 16 + quad * 4 + i;
                    if (colg > rowgA) sv = -1e30f;
                }
                pA[i] = __builtin_amdgcn_exp2f(sv);
                l2[0] += pA[i];
            }
            half2v lo = pkrtz(pA[0], pA[1]), hi = pkrtz(pA[2], pA[3]);
            paA[tn] = __builtin_shufflevector(lo, hi, 0, 1, 2, 3);
        }
        #pragma unroll
        for (int tn = 0; tn < 4; ++tn) {
            float pB[4];
            #pragma unroll
            for (int i = 0; i < 4; ++i) {
                float sv = stB[tn][i];
                if (j == qi) {
                    const int colg = j * 64 + tn * 16 + quad * 4 + i;
                    if (colg > rowgB) sv = -1e30f;
                }
                pB[i] = __builtin_amdgcn_exp2f(sv);
                l2[1] += pB[i];
            }
            half2v lo = pkrtz(pB[0], pB[1]), hi = pkrtz(pB[2], pB[3]);
            paB[tn] = __builtin_shufflevector(lo, hi, 0, 1, 2, 3);
        }

        // ---- O^T += V^T * P, both strips share V regs ----
        __builtin_amdgcn_s_setprio(1);
        #pragma unroll
        for (int tn = 0; tn < 4; ++tn) {
            half8 vl = *(const half8*)(&Vl[(tn * 64 + lane) * 8]);
            half8 vh = *(const half8*)(&Vl[2048 + (tn * 64 + lane) * 8]);
            half4 vf0 = __builtin_shufflevector(vl, vl, 0, 1, 2, 3);
            half4 vf1 = __builtin_shufflevector(vl, vl, 4, 5, 6, 7);
            half4 vf2 = __builtin_shufflevector(vh, vh, 0, 1, 2, 3);
            half4 vf3 = __builtin_shufflevector(vh, vh, 4, 5, 6, 7);
            o[0][0] = MFMA_F16_K16(vf0, paA[tn], o[0][0]);
            o[0][1] = MFMA_F16_K16(vf1, paA[tn], o[0][1]);
            o[0][2] = MFMA_F16_K16(vf2, paA[tn], o[0][2]);
            o[0][3] = MFMA_F16_K16(vf3, paA[tn], o[0][3]);
            o[1][0] = MFMA_F16_K16(vf0, paB[tn], o[1][0]);
            o[1][1] = MFMA_F16_K16(vf1, paB[tn], o[1][1]);
            o[1][2] = MFMA_F16_K16(vf2, paB[tn], o[1][2]);
            o[1][3] = MFMA_F16_K16(vf3, paB[tn], o[1][3]);
        }
        __builtin_amdgcn_s_setprio(0);

        // ---- flip: next DMA landed + all waves done reading cur ----
        asm volatile("s_waitcnt vmcnt(0)" ::: "memory");
        __builtin_amdgcn_sched_barrier(0);
        __syncthreads();
        cur ^= 1;
    }

    // ---- per-strip row sums + epilogue (direct stores) ----
    #pragma unroll
    for (int s2 = 0; s2 < 2; ++s2) {
        float l = l2[s2];
        l += __shfl_xor(l, 16);
        l += __shfl_xor(l, 32);
        const float inv = 1.0f / l;
        const int rowg = rowgA + s2 * 16;
        float* dst = Op + ((size_t)bh * Tc + rowg) * Dc;
        #pragma unroll
        for (int dn = 0; dn < 4; ++dn) {
            float4 r;
            r.x = o[s2][dn][0] * inv; r.y = o[s2][dn][1] * inv;
            r.z = o[s2][dn][2] * inv; r.w = o[s2][dn][3] * inv;
            *(float4*)(&dst[dn * 16 + quad * 4]) = r;
        }
    }
}

extern "C" void kernel_launch(void* const* d_in, const int* in_sizes, int n_in,
                              void* d_out, int out_size, void* d_ws, size_t ws_size,
                              hipStream_t stream) {
    const float* Q = (const float*)d_in[0];
    const float* K = (const float*)d_in[1];
    const float* V = (const float*)d_in[2];
    // d_in[3] = causal mask (analytic — unused)
    const float* C = (const float*)d_in[4];
    float* O = (float*)d_out;

    unsigned short* qfrag_w = (unsigned short*)d_ws;              // 8 MiB
    unsigned short* kfrag_w = qfrag_w + REGION;                   // 8 MiB
    _Float16*       vfrag_w = (_Float16*)(kfrag_w + REGION);      // 8 MiB
    unsigned short* cfrag_w = (unsigned short*)(vfrag_w + REGION);// 128 KiB

    holo_cfrag<<<dim3(16), dim3(256), 0, stream>>>(C, cfrag_w);
    holo_prep8<<<dim3(1024), dim3(256), 0, stream>>>(Q, K, V, cfrag_w, qfrag_w, kfrag_w, vfrag_w);
    holo_attn16<<<dim3(1024), dim3(128), 0, stream>>>(qfrag_w, kfrag_w, vfrag_w, O);
}